// Round 13
// baseline (157.853 us; speedup 1.0000x reference)
//
#include <hip/hip_runtime.h>
#include <math.h>

#define L_SEQ 8192
#define H_DIM 1024
#define N_DIM 1024
#define K2    2048          // packed K = 2*H = 2*N
#define NCHUNK 256
#define CHUNK 32

typedef unsigned short u16;
typedef __attribute__((ext_vector_type(8))) __bf16 bf16x8;
typedef __attribute__((ext_vector_type(4))) float  f32x4;

__device__ __forceinline__ u16 f2bf(float x) {
    unsigned int u = __float_as_uint(x);
    u = (u + 0x7fffu + ((u >> 16) & 1u)) >> 16;   // RNE
    return (u16)u;
}
__device__ __forceinline__ float bf2f(u16 h) {
    return __uint_as_float(((unsigned int)h) << 16);
}

__device__ __forceinline__ void gload_lds16(const void* g, void* s) {
    __builtin_amdgcn_global_load_lds(
        (const __attribute__((address_space(1))) unsigned int*)g,
        (__attribute__((address_space(3))) unsigned int*)s, 16, 0, 0);
}

// ---------------------------------------------------------------------------
// Pack u -> A' bf16 [L][2H]: cols [0,1024)=u_r, [1024,2048)=u_i
// ---------------------------------------------------------------------------
__global__ void pack_u(const float* __restrict__ R, const float* __restrict__ I,
                       u16* __restrict__ A) {
    size_t t = (size_t)blockIdx.x * 256 + threadIdx.x;
    size_t base = t * 4;                      // over L*H
    int lrow = (int)(base >> 10);
    int h    = (int)(base & 1023);
    float4 r  = *reinterpret_cast<const float4*>(R + base);
    float4 im = *reinterpret_cast<const float4*>(I + base);
    u16* p0 = A + ((size_t)lrow << 11) + h;
    *reinterpret_cast<ushort4*>(p0) =
        make_ushort4(f2bf(r.x), f2bf(r.y), f2bf(r.z), f2bf(r.w));
    *reinterpret_cast<ushort4*>(p0 + 1024) =
        make_ushort4(f2bf(im.x), f2bf(im.y), f2bf(im.z), f2bf(im.w));
}

// ---------------------------------------------------------------------------
// B_norm pack -> Bp bf16 [2N][2H]
// ---------------------------------------------------------------------------
__global__ void bnorm_pack(const float* __restrict__ Br, const float* __restrict__ Bi,
                           const float* __restrict__ G, u16* __restrict__ Bp) {
    size_t t = (size_t)blockIdx.x * 256 + threadIdx.x;
    size_t base = t * 4;                      // over N*H
    int n = (int)(base >> 10);
    int h = (int)(base & 1023);
    float g = G[n];
    float sg, cg;
    sincosf(g, &sg, &cg);
    float4 br = *reinterpret_cast<const float4*>(Br + base);
    float4 bi = *reinterpret_cast<const float4*>(Bi + base);
    float nr0 = br.x * cg - bi.x * sg, ni0 = br.x * sg + bi.x * cg;
    float nr1 = br.y * cg - bi.y * sg, ni1 = br.y * sg + bi.y * cg;
    float nr2 = br.z * cg - bi.z * sg, ni2 = br.z * sg + bi.z * cg;
    float nr3 = br.w * cg - bi.w * sg, ni3 = br.w * sg + bi.w * cg;
    u16* row0 = Bp + (size_t)n * K2;
    u16* row1 = Bp + (size_t)(N_DIM + n) * K2;
    *reinterpret_cast<ushort4*>(row0 + h) =
        make_ushort4(f2bf(nr0), f2bf(nr1), f2bf(nr2), f2bf(nr3));
    *reinterpret_cast<ushort4*>(row0 + 1024 + h) =
        make_ushort4(f2bf(-ni0), f2bf(-ni1), f2bf(-ni2), f2bf(-ni3));
    *reinterpret_cast<ushort4*>(row1 + h) =
        make_ushort4(f2bf(ni0), f2bf(ni1), f2bf(ni2), f2bf(ni3));
    *reinterpret_cast<ushort4*>(row1 + 1024 + h) =
        make_ushort4(f2bf(nr0), f2bf(nr1), f2bf(nr2), f2bf(nr3));
}

// ---------------------------------------------------------------------------
// C pack -> Cp bf16 [H][2N]: row h = [ C_r[h][:] | -C_i[h][:] ]
// ---------------------------------------------------------------------------
__global__ void pack_C(const float* __restrict__ Cr, const float* __restrict__ Ci,
                       u16* __restrict__ Cp) {
    size_t t = (size_t)blockIdx.x * 256 + threadIdx.x;
    size_t base = t * 4;                      // over H*N
    int h = (int)(base >> 10);
    int n = (int)(base & 1023);
    float4 cr = *reinterpret_cast<const float4*>(Cr + base);
    float4 ci = *reinterpret_cast<const float4*>(Ci + base);
    u16* row = Cp + (size_t)h * K2;
    *reinterpret_cast<ushort4*>(row + n) =
        make_ushort4(f2bf(cr.x), f2bf(cr.y), f2bf(cr.z), f2bf(cr.w));
    *reinterpret_cast<ushort4*>(row + 1024 + n) =
        make_ushort4(f2bf(-ci.x), f2bf(-ci.y), f2bf(-ci.z), f2bf(-ci.w));
}

// ---------------------------------------------------------------------------
// GEMM1: faithful m201 8-phase, 256x256 tile, BK=64, 8 waves (2Mx4N).
// LDS: 2 dbuf x {A-half0, A-half1, B-half0, B-half1} x 16KB = 128KB.
// Quadrants per tile: Q(qa,qb) with qa = mi-half, qb = nj-half; order
// (0,0),(1,0),(1,1),(0,1). Per phase: {ds-reads for THIS phase's quadrant
// (12/8/4/0 b128), stage 1 half, [vmcnt@p4/p8], barrier, lgkm0, 16 MFMA
// (setprio), barrier}. Reads precede the opening barrier (latency hides
// under the rendezvous); residency for a dbuf is established by the PRIOR
// p4/p8 vmcnt+barrier, so no read ever precedes its residency barrier
// (r9's bug). Stage cadence: p1 B0(T1), p2 B1(T1), p3 A0(T+2), p4 A1(T+2),
// p5 B0(T+2), p6 B1(T+2), p7 A0(T+3), p8 A1(T+3) — each stage lands >=1
// barrier after its region's last reader (A-halves read p1-p2, B-halves
// p1&p3 per tile). vmcnt(4) at p4/p8: queue = 6 halves (12 loads); leaving
// the newest 2 halves drains through the target tile's last half. Tails:
// p4 uses vmcnt(0) when t0+2>=nt; p8 skipped on the last iter.
// 3-bit slot swizzle (slot ^ (row&7)), both-sides. Out = A*B^T, bf16.
// ---------------------------------------------------------------------------
__global__ __launch_bounds__(512, 2) void gemm_pipe8(
    const u16* __restrict__ A, const u16* __restrict__ B, int Klen, int lda,
    u16* __restrict__ OutB, int ldo) {
    constexpr int HALF = 16384;            // 128 rows x 128B
    constexpr int DBUF = 4 * HALF;         // 64KB
    __shared__ __attribute__((aligned(128))) char lds[2 * DBUF];
    const int tid = threadIdx.x;
    const int l   = tid & 63;
    const int w   = tid >> 6;
    const int wm  = w >> 2;            // 0..1
    const int wn  = w & 3;             // 0..3
    const long bm = (long)blockIdx.x * 256;
    const long bn = (long)blockIdx.y * 256;

    f32x4 acc[8][4];
#pragma unroll
    for (int i = 0; i < 8; ++i)
#pragma unroll
        for (int j = 0; j < 4; ++j) acc[i][j] = (f32x4){0.f, 0.f, 0.f, 0.f};

    // staging: one gload = 512 thr x 16B = 8KB = 64 rows; half = 2 gloads.
    const int    lr        = tid >> 3;
    const int    swzcol    = (((tid & 7) ^ (lr & 7)) << 4);
    const size_t rowstride = (size_t)lda * 2;
    const size_t a_src0    = (size_t)(bm + lr) * rowstride + swzcol;
    const size_t b_src0    = (size_t)(bn + lr) * rowstride + swzcol;
    const char*  Agb       = (const char*)A;
    const char*  Bgb       = (const char*)B;
    const int nt = Klen / 64;

    auto STAGE_A = [&](int kt, int h) {
        if (kt >= nt) return;
        const size_t kofs = (size_t)kt * 128;
        char* d = lds + (kt & 1) * DBUF + h * HALF + tid * 16;
#pragma unroll
        for (int j = 0; j < 2; ++j)
            gload_lds16(Agb + a_src0 + (size_t)(h * 128 + j * 64) * rowstride + kofs,
                        d + j * 8192);
    };
    auto STAGE_B = [&](int kt, int h) {
        if (kt >= nt) return;
        const size_t kofs = (size_t)kt * 128;
        char* d = lds + (kt & 1) * DBUF + 2 * HALF + h * HALF + tid * 16;
#pragma unroll
        for (int j = 0; j < 2; ++j)
            gload_lds16(Bgb + b_src0 + (size_t)(h * 128 + j * 64) * rowstride + kofs,
                        d + j * 8192);
    };

    const int l15   = l & 15;
    const int lslot = l >> 4;

    // A-sub qa of wave wm: within-half rows qa*64 + mi*16 + l15 (mi<4)
    auto READ_Asub = [&](bf16x8 (&af)[8], const char* db, int qa) {
        const char* base = db + wm * HALF;
#pragma unroll
        for (int mi = 0; mi < 4; ++mi)
#pragma unroll
            for (int kk = 0; kk < 2; ++kk) {
                int rw  = qa * 64 + mi * 16 + l15;
                int sl3 = ((kk << 2) | lslot) ^ (rw & 7);
                af[mi * 2 + kk] =
                    *reinterpret_cast<const bf16x8*>(base + rw * 128 + sl3 * 16);
            }
    };
    // B-sub qb of wave wn: B-half (wn>>1), within-half rows
    // (wn&1)*64 + qb*32 + nj*16 + l15 (nj<2)
    auto READ_Bsub = [&](bf16x8 (&bg)[4], const char* db, int qb) {
        const char* base = db + 2 * HALF + (wn >> 1) * HALF;
#pragma unroll
        for (int nj = 0; nj < 2; ++nj)
#pragma unroll
            for (int kk = 0; kk < 2; ++kk) {
                int rw  = (wn & 1) * 64 + qb * 32 + nj * 16 + l15;
                int sl3 = ((kk << 2) | lslot) ^ (rw & 7);
                bg[nj * 2 + kk] =
                    *reinterpret_cast<const bf16x8*>(base + rw * 128 + sl3 * 16);
            }
    };
    auto MFMA_Q = [&](bf16x8 (&af)[8], bf16x8 (&bg)[4], int qa, int qb) {
        __builtin_amdgcn_s_setprio(1);
#pragma unroll
        for (int mi = 0; mi < 4; ++mi)
#pragma unroll
            for (int nj = 0; nj < 2; ++nj)
#pragma unroll
                for (int kk = 0; kk < 2; ++kk)
                    acc[qa * 4 + mi][qb * 2 + nj] =
                        __builtin_amdgcn_mfma_f32_16x16x32_bf16(
                            af[mi * 2 + kk], bg[nj * 2 + kk],
                            acc[qa * 4 + mi][qb * 2 + nj], 0, 0, 0);
        __builtin_amdgcn_s_setprio(0);
    };

#define SBAR  do { __builtin_amdgcn_sched_barrier(0);                        \
    __builtin_amdgcn_s_barrier();                                            \
    __builtin_amdgcn_sched_barrier(0); } while (0)
#define LGKM0 do { asm volatile("s_waitcnt lgkmcnt(0)" ::: "memory");        \
    __builtin_amdgcn_sched_barrier(0); } while (0)

    // Prologue: T0 all 4 halves + A0(1),A1(1) (what iter -1's p7/p8 stage).
    // vmcnt(4) leaves A0(1),A1(1) -> T0 resident; barrier publishes.
    STAGE_A(0, 0); STAGE_A(0, 1); STAGE_B(0, 0); STAGE_B(0, 1);
    STAGE_A(1, 0); STAGE_A(1, 1);
    asm volatile("s_waitcnt vmcnt(4)" ::: "memory");
    SBAR;

    bf16x8 afE[8], afO[8], bgE[4], bgO[4];
    const int niter = nt / 2;

    for (int i = 0; i < niter; ++i) {
        const int t0 = 2 * i;
        const int t1 = t0 + 1;
        const char* d0 = lds + (t0 & 1) * DBUF;   // dbuf0 (even tile)
        const char* d1 = lds + (t1 & 1) * DBUF;   // dbuf1 (odd tile)
        // ---- p1: reads A-sub0+B-sub0 (12) | stage B0(T1) ------------------
        READ_Asub(afE, d0, 0);
        READ_Bsub(bgE, d0, 0);
        STAGE_B(t1, 0);
        SBAR; LGKM0;
        MFMA_Q(afE, bgE, 0, 0);
        SBAR;
        // ---- p2: reads A-sub1 (8) | stage B1(T1) --------------------------
        READ_Asub(afO, d0, 1);
        STAGE_B(t1, 1);
        SBAR; LGKM0;
        MFMA_Q(afO, bgE, 1, 0);
        SBAR;
        // ---- p3: reads B-sub1 (4) | stage A0(T+2) -------------------------
        READ_Bsub(bgO, d0, 1);
        STAGE_A(t0 + 2, 0);
        SBAR; LGKM0;
        MFMA_Q(afO, bgO, 1, 1);
        SBAR;
        // ---- p4: stage A1(T+2) | vmcnt | MFMA Q(0,1) ----------------------
        STAGE_A(t0 + 2, 1);
        if (t0 + 2 < nt) asm volatile("s_waitcnt vmcnt(4)" ::: "memory");
        else             asm volatile("s_waitcnt vmcnt(0)" ::: "memory");
        SBAR;
        MFMA_Q(afE, bgO, 0, 1);
        SBAR;
        // ---- p5: reads dbuf1 A-sub0+B-sub0 | stage B0(T+2) ----------------
        READ_Asub(afE, d1, 0);
        READ_Bsub(bgE, d1, 0);
        STAGE_B(t0 + 2, 0);
        SBAR; LGKM0;
        MFMA_Q(afE, bgE, 0, 0);
        SBAR;
        // ---- p6: reads A-sub1 | stage B1(T+2) -----------------------------
        READ_Asub(afO, d1, 1);
        STAGE_B(t0 + 2, 1);
        SBAR; LGKM0;
        MFMA_Q(afO, bgE, 1, 0);
        SBAR;
        // ---- p7: reads B-sub1 | stage A0(T+3) -----------------------------
        READ_Bsub(bgO, d1, 1);
        STAGE_A(t1 + 2, 0);
        SBAR; LGKM0;
        MFMA_Q(afO, bgO, 1, 1);
        SBAR;
        // ---- p8: stage A1(T+3) | vmcnt | MFMA Q(0,1) ----------------------
        STAGE_A(t1 + 2, 1);
        if (i + 1 < niter) asm volatile("s_waitcnt vmcnt(4)" ::: "memory");
        SBAR;
        MFMA_Q(afE, bgO, 0, 1);
        SBAR;
    }
#undef SBAR
#undef LGKM0

    // C/D layout: col = lane&15, row = (lane>>4)*4 + reg
#pragma unroll
    for (int mi = 0; mi < 8; ++mi) {
        const long row0 = bm + wm * 128 + mi * 16 + ((l >> 4) << 2);
#pragma unroll
        for (int ni = 0; ni < 4; ++ni) {
            const long col = bn + wn * 64 + ni * 16 + l15;
#pragma unroll
            for (int r = 0; r < 4; ++r)
                OutB[(size_t)(row0 + r) * ldo + col] = f2bf(acc[mi][ni][r]);
        }
    }
}

// ---------------------------------------------------------------------------
// GEMM2 (round-11 proven): 128x128 tile, 4 waves (2Mx2N), 64KB LDS ->
// 2 blocks/CU, interleaved 2-barrier schedule, counted vmcnt(4).
// Fused epilogue: OutF = acc + Dv[col] * Ur[row,col].
// ---------------------------------------------------------------------------
__global__ __launch_bounds__(256, 2) void gemm_small(
    const u16* __restrict__ A, const u16* __restrict__ B, int Klen, int lda,
    float* __restrict__ OutF, int ldo,
    const float* __restrict__ Dv, const float* __restrict__ Ur) {
    constexpr int ABYTES = 128 * 128;          // 16KB
    constexpr int SLOT   = 2 * ABYTES;         // 32KB (A+B)
    __shared__ __attribute__((aligned(128))) char lds[2 * SLOT];  // 64KB
    const int tid = threadIdx.x;
    const int l   = tid & 63;
    const int w   = tid >> 6;          // 0..3
    const int wm  = w >> 1;            // 0..1
    const int wn  = w & 1;             // 0..1
    const long bm = (long)blockIdx.x * 128;
    const long bn = (long)blockIdx.y * 128;

    f32x4 acc[4][4];
#pragma unroll
    for (int i = 0; i < 4; ++i)
#pragma unroll
        for (int j = 0; j < 4; ++j) acc[i][j] = (f32x4){0.f, 0.f, 0.f, 0.f};

    const int    lr        = tid >> 3;                    // 0..31
    const int    swzcol    = (((tid & 7) ^ (lr & 7)) << 4);
    const size_t rowstride = (size_t)lda * 2;
    const size_t a_src0    = (size_t)(bm + lr) * rowstride + swzcol;
    const size_t b_src0    = (size_t)(bn + lr) * rowstride + swzcol;
    const char*  Agb       = (const char*)A;
    const char*  Bgb       = (const char*)B;
    const int nt = Klen / 64;

    auto STAGE_A = [&](int kt, int h) {
        if (kt >= nt) return;
        const size_t kofs = (size_t)kt * 128;
        char* d = lds + (kt & 1) * SLOT + h * 8192 + tid * 16;
#pragma unroll
        for (int j = 0; j < 2; ++j)
            gload_lds16(Agb + a_src0 + (size_t)(h * 64 + j * 32) * rowstride + kofs,
                        d + j * 4096);
    };
    auto STAGE_B = [&](int kt, int h) {
        if (kt >= nt) return;
        const size_t kofs = (size_t)kt * 128;
        char* d = lds + (kt & 1) * SLOT + ABYTES + h * 8192 + tid * 16;
#pragma unroll
        for (int j = 0; j < 2; ++j)
            gload_lds16(Bgb + b_src0 + (size_t)(h * 64 + j * 32) * rowstride + kofs,
                        d + j * 4096);
    };

    const int l15   = l & 15;
    const int lslot = l >> 4;

    auto READ_A = [&](bf16x8 (&af)[4], const char* lA, int kk) {
#pragma unroll
        for (int mi = 0; mi < 4; ++mi) {
            int r   = wm * 64 + mi * 16 + l15;
            int sl3 = ((kk << 2) | lslot) ^ (r & 7);
            af[mi]  = *reinterpret_cast<const bf16x8*>(lA + r * 128 + sl3 * 16);
        }
    };
    auto READ_B = [&](bf16x8 (&bg)[4], const char* lB, int kk) {
#pragma unroll
        for (int ni = 0; ni < 4; ++ni) {
            int r   = wn * 64 + ni * 16 + l15;
            int sl3 = ((kk << 2) | lslot) ^ (r & 7);
            bg[ni]  = *reinterpret_cast<const bf16x8*>(lB + r * 128 + sl3 * 16);
        }
    };
    auto MFMA_Q = [&](bf16x8 (&af)[4], bf16x8 (&bg)[4], int qn) {
        __builtin_amdgcn_s_setprio(1);
#pragma unroll
        for (int mi = 0; mi < 4; ++mi)
#pragma unroll
            for (int nj = 0; nj < 2; ++nj)
                acc[mi][qn * 2 + nj] = __builtin_amdgcn_mfma_f32_16x16x32_bf16(
                    af[mi], bg[qn * 2 + nj], acc[mi][qn * 2 + nj], 0, 0, 0);
        __builtin_amdgcn_s_setprio(0);
    };

#define SBAR  do { __builtin_amdgcn_sched_barrier(0);                        \
    __builtin_amdgcn_s_barrier();                                            \
    __builtin_amdgcn_sched_barrier(0); } while (0)
#define LGKM0 do { asm volatile("s_waitcnt lgkmcnt(0)" ::: "memory");        \
    __builtin_amdgcn_sched_barrier(0); } while (0)

    STAGE_A(0, 0); STAGE_B(0, 0); STAGE_A(0, 1); STAGE_B(0, 1);
    STAGE_A(1, 0); STAGE_B(1, 0);
    asm volatile("s_waitcnt vmcnt(4)" ::: "memory");
    SBAR;

    bf16x8 af0[4], af1[4], bg0[4], bg1[4];

    for (int t = 0; t < nt; ++t) {
        const char* lA = lds + (t & 1) * SLOT;
        const char* lB = lA + ABYTES;
        READ_A(af0, lA, 0);
        READ_B(bg0, lB, 0);
        STAGE_A(t + 1, 1);
        LGKM0;
        MFMA_Q(af0, bg0, 0);
        READ_A(af1, lA, 1);
        READ_B(bg1, lB, 1);
        STAGE_B(t + 1, 1);
        MFMA_Q(af0, bg0, 1);
        LGKM0;
        SBAR;                              // B1: all waves' slot-s reads done
        STAGE_A(t + 2, 0);
        MFMA_Q(af1, bg1, 0);
        STAGE_B(t + 2, 0);
        MFMA_Q(af1, bg1, 1);
        if (t < nt - 2) asm volatile("s_waitcnt vmcnt(4)" ::: "memory");
        else            asm volatile("s_waitcnt vmcnt(0)" ::: "memory");
        SBAR;                              // B2: tile t+1 resident, all waves
    }
#undef SBAR
#undef LGKM0

    // epilogue with fused D*u_r
#pragma unroll
    for (int mi = 0; mi < 4; ++mi) {
        const long row0 = bm + wm * 64 + mi * 16 + ((l >> 4) << 2);
#pragma unroll
        for (int ni = 0; ni < 4; ++ni) {
            const long col = bn + wn * 64 + ni * 16 + l15;
            const float d = Dv[col];
#pragma unroll
            for (int r = 0; r < 4; ++r) {
                size_t o = (size_t)(row0 + r) * ldo + col;
                OutF[o] = acc[mi][ni][r] + d * Ur[o];
            }
        }
    }
}

// ---------------------------------------------------------------------------
// Scan pass A (read-only): per-(chunk, channel-pair) final states only.
// ---------------------------------------------------------------------------
__global__ void scan_sum(const u16* __restrict__ X,
                         const float* __restrict__ nu_log,
                         const float* __restrict__ theta_log,
                         float* __restrict__ bcr, float* __restrict__ bci) {
    int n0 = (blockIdx.y * 256 + threadIdx.x) * 2;   // channel pair
    int c  = blockIdx.x;
    float lr0, li0, lr1, li1;
    {
        float m0 = expf(-expf(nu_log[n0]));
        float t0 = expf(theta_log[n0]);
        float s0, c0; sincosf(t0, &s0, &c0);
        lr0 = m0 * c0; li0 = m0 * s0;
        float m1 = expf(-expf(nu_log[n0 + 1]));
        float t1 = expf(theta_log[n0 + 1]);
        float s1, c1; sincosf(t1, &s1, &c1);
        lr1 = m1 * c1; li1 = m1 * s1;
    }
    float sr0 = 0.f, si0 = 0.f, sr1 = 0.f, si1 = 0.f;
    size_t base = (size_t)c * CHUNK * K2 + n0;
    for (int j = 0; j < CHUNK; ++j) {
        size_t idx = base + (size_t)j * K2;
        unsigned int ru = *reinterpret_cast<const unsigned int*>(X + idx);
        unsigned int iu = *reinterpret_cast<const unsigned int*>(X + idx + 1024);
        float br0 = bf2f((u16)ru), br1 = bf2f((u16)(ru >> 16));
        float bi0 = bf2f((u16)iu), bi1 = bf2f((u16)(iu >> 16));
        float nr0 = lr0 * sr0 - li0 * si0 + br0;
        float ni0 = lr0 * si0 + li0 * sr0 + bi0;
        sr0 = nr0; si0 = ni0;
        float nr1 = lr1 * sr1 - li1 * si1 + br1;
        float ni1 = lr1 * si1 + li1 * sr1 + bi1;
        sr1 = nr1; si1 = ni1;
    }
    bcr[(size_t)n0 * NCHUNK + c] = sr0; bci[(size_t)n0 * NCHUNK + c] = si0;
    bcr[(size_t)(n0 + 1) * NCHUNK + c] = sr1; bci[(size_t)(n0 + 1) * NCHUNK + c] = si1;
}

// ---------------------------------------------------------------------------
// Scan pass B: wave-parallel scan over NCHUNK=256 chunk summaries.
// One wave per channel; lane owns 4 chunks; 6-step shfl_up scan.
// ---------------------------------------------------------------------------
__global__ void scan_carry(const float* __restrict__ bcr, const float* __restrict__ bci,
                           const float* __restrict__ nu_log,
                           const float* __restrict__ theta_log,
                           float* __restrict__ car, float* __restrict__ cai) {
    const int lane = threadIdx.x & 63;
    const int n    = blockIdx.x * 4 + (threadIdx.x >> 6);
    float mag = expf(-(float)CHUNK * expf(nu_log[n]));
    float ang = (float)CHUNK * expf(theta_log[n]);
    float sL, cL; sincosf(ang, &sL, &cL);
    const float Lr = mag * cL, Li = mag * sL;
    const size_t base = (size_t)n * NCHUNK + lane * 4;
    float4 br4 = *reinterpret_cast<const float4*>(bcr + base);
    float4 bi4 = *reinterpret_cast<const float4*>(bci + base);
    float br = br4.x, bi = bi4.x;
    { float tr = Lr * br - Li * bi + br4.y, ti = Lr * bi + Li * br + bi4.y; br = tr; bi = ti; }
    { float tr = Lr * br - Li * bi + br4.z, ti = Lr * bi + Li * br + bi4.z; br = tr; bi = ti; }
    { float tr = Lr * br - Li * bi + br4.w, ti = Lr * bi + Li * br + bi4.w; br = tr; bi = ti; }
    float L2r = Lr * Lr - Li * Li, L2i = 2.f * Lr * Li;
    float Ar = L2r * L2r - L2i * L2i, Ai = 2.f * L2r * L2i;   // L^4
#pragma unroll
    for (int d = 1; d < 64; d <<= 1) {
        float pAr = __shfl_up(Ar, d);
        float pAi = __shfl_up(Ai, d);
        float pbr = __shfl_up(br, d);
        float pbi = __shfl_up(bi, d);
        if (lane >= d) {
            float nbr = Ar * pbr - Ai * pbi + br;
            float nbi = Ar * pbi + Ai * pbr + bi;
            float nAr = Ar * pAr - Ai * pAi;
            float nAi = Ar * pAi + Ai * pAr;
            br = nbr; bi = nbi; Ar = nAr; Ai = nAi;
        }
    }
    float sr = __shfl_up(br, 1);
    float si = __shfl_up(bi, 1);
    if (lane == 0) { sr = 0.f; si = 0.f; }
    float4 or4, oi4;
    or4.x = sr; oi4.x = si;
    { float tr = Lr * sr - Li * si + br4.x, ti = Lr * si + Li * sr + bi4.x; sr = tr; si = ti; }
    or4.y = sr; oi4.y = si;
    { float tr = Lr * sr - Li * si + br4.y, ti = Lr * si + Li * sr + bi4.y; sr = tr; si = ti; }
    or4.z = sr; oi4.z = si;
    { float tr = Lr * sr - Li * si + br4.z, ti = Lr * si + Li * sr + bi4.z; sr = tr; si = ti; }
    or4.w = sr; oi4.w = si;
    *reinterpret_cast<float4*>(car + base) = or4;
    *reinterpret_cast<float4*>(cai + base) = oi4;
}

// ---------------------------------------------------------------------------
// Scan pass C: re-scan each chunk seeded with carry-in; write final x (bf16).
// ---------------------------------------------------------------------------
__global__ void scan_apply(u16* __restrict__ X,
                           const float* __restrict__ nu_log,
                           const float* __restrict__ theta_log,
                           const float* __restrict__ car, const float* __restrict__ cai) {
    int n0 = (blockIdx.y * 256 + threadIdx.x) * 2;
    int c  = blockIdx.x;
    float lr0, li0, lr1, li1;
    {
        float m0 = expf(-expf(nu_log[n0]));
        float t0 = expf(theta_log[n0]);
        float s0, c0; sincosf(t0, &s0, &c0);
        lr0 = m0 * c0; li0 = m0 * s0;
        float m1 = expf(-expf(nu_log[n0 + 1]));
        float t1 = expf(theta_log[n0 + 1]);
        float s1, c1; sincosf(t1, &s1, &c1);
        lr1 = m1 * c1; li1 = m1 * s1;
    }
    float sr0 = car[(size_t)n0 * NCHUNK + c],       si0 = cai[(size_t)n0 * NCHUNK + c];
    float sr1 = car[(size_t)(n0 + 1) * NCHUNK + c], si1 = cai[(size_t)(n0 + 1) * NCHUNK + c];
    size_t base = (size_t)c * CHUNK * K2 + n0;
    for (int j = 0; j < CHUNK; ++j) {
        size_t idx = base + (size_t)j * K2;
        unsigned int ru = *reinterpret_cast<const unsigned int*>(X + idx);
        unsigned int iu = *reinterpret_cast<const unsigned int*>(X + idx + 1024);
        float br0 = bf2f((u16)ru), br1 = bf2f((u16)(ru >> 16));
        float bi0 = bf2f((u16)iu), bi1 = bf2f((u16)(iu >> 16));
        float nr0 = lr0 * sr0 - li0 * si0 + br0;
        float ni0 = lr0 * si0 + li0 * sr0 + bi0;
        sr0 = nr0; si0 = ni0;
        float nr1 = lr1 * sr1 - li1 * si1 + br1;
        float ni1 = lr1 * si1 + li1 * sr1 + bi1;
        sr1 = nr1; si1 = ni1;
        *reinterpret_cast<unsigned int*>(X + idx) =
            (unsigned int)f2bf(sr0) | ((unsigned int)f2bf(sr1) << 16);
        *reinterpret_cast<unsigned int*>(X + idx + 1024) =
            (unsigned int)f2bf(si0) | ((unsigned int)f2bf(si1) << 16);
    }
}

// ---------------------------------------------------------------------------
// Launch
// ---------------------------------------------------------------------------
extern "C" void kernel_launch(void* const* d_in, const int* in_sizes, int n_in,
                              void* d_out, int out_size, void* d_ws, size_t ws_size,
                              hipStream_t stream) {
    (void)in_sizes; (void)n_in; (void)out_size; (void)ws_size;
    const float* input_real = (const float*)d_in[0];
    const float* input_imag = (const float*)d_in[1];
    const float* nu_log     = (const float*)d_in[2];
    const float* theta_log  = (const float*)d_in[3];
    const float* B_real     = (const float*)d_in[4];
    const float* B_imag     = (const float*)d_in[5];
    const float* C_real     = (const float*)d_in[6];
    const float* C_imag     = (const float*)d_in[7];
    const float* D          = (const float*)d_in[8];
    const float* gamma_log  = (const float*)d_in[9];
    float* y = (float*)d_out;

    // Workspace layout (bytes):
    // [2M, 34M)  A' bf16 [8192][2048]  (dead after gemm1)
    //   [2M, 6M)   Cp aliases A' head  (alive after pack_C)
    // [34M, 42M) Bp bf16 [2048][2048]  (dead after gemm1)
    //   [34M, 38M) bcr/bci/car/cai (4 x 1MB) alias Bp (alive after gemm1)
    // [42M, 74M) X  bf16 [8192][2048]  (Bu -> x in place)
    char* ws = (char*)d_ws;
    u16* Ap   = (u16*)(ws + ((size_t)2 << 20));
    u16* Cp   = Ap;                                 // alias: used after gemm1
    u16* Bp   = (u16*)(ws + ((size_t)34 << 20));
    float* bcr = (float*)(ws + ((size_t)34 << 20)); // alias Bp: used after gemm1
    float* bci = bcr + NCHUNK * N_DIM;
    float* car = bci + NCHUNK * N_DIM;
    float* cai = car + NCHUNK * N_DIM;
    u16* X    = (u16*)(ws + ((size_t)42 << 20));

    pack_u<<<(L_SEQ * H_DIM / 4) / 256, 256, 0, stream>>>(input_real, input_imag, Ap);
    bnorm_pack<<<(N_DIM * H_DIM / 4) / 256, 256, 0, stream>>>(B_real, B_imag, gamma_log, Bp);
    // GEMM1: 8-phase 256x256, grid 32x8 = 256 blocks (1/CU), K=2048
    gemm_pipe8<<<dim3(L_SEQ / 256, K2 / 256), 512, 0, stream>>>(
        Ap, Bp, K2, K2, X, K2);
    scan_sum<<<dim3(NCHUNK, N_DIM / 512), 256, 0, stream>>>(
        X, nu_log, theta_log, bcr, bci);
    scan_carry<<<N_DIM / 4, 256, 0, stream>>>(bcr, bci, nu_log, theta_log, car, cai);
    scan_apply<<<dim3(NCHUNK, N_DIM / 512), 256, 0, stream>>>(
        X, nu_log, theta_log, car, cai);
    pack_C<<<(H_DIM * N_DIM / 4) / 256, 256, 0, stream>>>(C_real, C_imag, Cp);
    // GEMM2: 128x128 tile, grid 64x8 = 512 blocks (2/CU), K=2048, fused D*u
    gemm_small<<<dim3(L_SEQ / 128, H_DIM / 128), 256, 0, stream>>>(
        X, Cp, K2, K2, y, H_DIM, D, input_real);
}

// Round 14
// 152.255 us; speedup vs baseline: 1.0368x; 1.0368x over previous
//
#include <hip/hip_runtime.h>
#include <math.h>

#define L_SEQ 8192
#define H_DIM 1024
#define N_DIM 1024
#define K2    2048          // packed K = 2*H = 2*N
#define NCHUNK 256
#define CHUNK 32

typedef unsigned short u16;
typedef __attribute__((ext_vector_type(8))) __bf16 bf16x8;
typedef __attribute__((ext_vector_type(4))) float  f32x4;

__device__ __forceinline__ u16 f2bf(float x) {
    unsigned int u = __float_as_uint(x);
    u = (u + 0x7fffu + ((u >> 16) & 1u)) >> 16;   // RNE
    return (u16)u;
}
__device__ __forceinline__ float bf2f(u16 h) {
    return __uint_as_float(((unsigned int)h) << 16);
}

__device__ __forceinline__ void gload_lds16(const void* g, void* s) {
    __builtin_amdgcn_global_load_lds(
        (const __attribute__((address_space(1))) unsigned int*)g,
        (__attribute__((address_space(3))) unsigned int*)s, 16, 0, 0);
}

// ---------------------------------------------------------------------------
// Merged pack: blocks [0, 8192) do pack_u (A' bf16 [L][2H]); blocks
// [8192, 9216) do bnorm_pack (Bp bf16 [2N][2H]). Block-uniform branch.
// ---------------------------------------------------------------------------
__global__ void pack_ub(const float* __restrict__ R, const float* __restrict__ I,
                        const float* __restrict__ Br, const float* __restrict__ Bi,
                        const float* __restrict__ G,
                        u16* __restrict__ A, u16* __restrict__ Bp) {
    if (blockIdx.x < (L_SEQ * H_DIM / 4) / 256) {
        size_t t = (size_t)blockIdx.x * 256 + threadIdx.x;
        size_t base = t * 4;                      // over L*H
        int lrow = (int)(base >> 10);
        int h    = (int)(base & 1023);
        float4 r  = *reinterpret_cast<const float4*>(R + base);
        float4 im = *reinterpret_cast<const float4*>(I + base);
        u16* p0 = A + ((size_t)lrow << 11) + h;
        *reinterpret_cast<ushort4*>(p0) =
            make_ushort4(f2bf(r.x), f2bf(r.y), f2bf(r.z), f2bf(r.w));
        *reinterpret_cast<ushort4*>(p0 + 1024) =
            make_ushort4(f2bf(im.x), f2bf(im.y), f2bf(im.z), f2bf(im.w));
    } else {
        size_t t = (size_t)(blockIdx.x - (L_SEQ * H_DIM / 4) / 256) * 256 + threadIdx.x;
        size_t base = t * 4;                      // over N*H
        int n = (int)(base >> 10);
        int h = (int)(base & 1023);
        float g = G[n];
        float sg, cg;
        sincosf(g, &sg, &cg);
        float4 br = *reinterpret_cast<const float4*>(Br + base);
        float4 bi = *reinterpret_cast<const float4*>(Bi + base);
        float nr0 = br.x * cg - bi.x * sg, ni0 = br.x * sg + bi.x * cg;
        float nr1 = br.y * cg - bi.y * sg, ni1 = br.y * sg + bi.y * cg;
        float nr2 = br.z * cg - bi.z * sg, ni2 = br.z * sg + bi.z * cg;
        float nr3 = br.w * cg - bi.w * sg, ni3 = br.w * sg + bi.w * cg;
        u16* row0 = Bp + (size_t)n * K2;
        u16* row1 = Bp + (size_t)(N_DIM + n) * K2;
        *reinterpret_cast<ushort4*>(row0 + h) =
            make_ushort4(f2bf(nr0), f2bf(nr1), f2bf(nr2), f2bf(nr3));
        *reinterpret_cast<ushort4*>(row0 + 1024 + h) =
            make_ushort4(f2bf(-ni0), f2bf(-ni1), f2bf(-ni2), f2bf(-ni3));
        *reinterpret_cast<ushort4*>(row1 + h) =
            make_ushort4(f2bf(ni0), f2bf(ni1), f2bf(ni2), f2bf(ni3));
        *reinterpret_cast<ushort4*>(row1 + 1024 + h) =
            make_ushort4(f2bf(nr0), f2bf(nr1), f2bf(nr2), f2bf(nr3));
    }
}

// ---------------------------------------------------------------------------
// C pack -> Cp bf16 [H][2N]: row h = [ C_r[h][:] | -C_i[h][:] ]
// (runs after gemm1: Cp aliases A' head)
// ---------------------------------------------------------------------------
__global__ void pack_C(const float* __restrict__ Cr, const float* __restrict__ Ci,
                       u16* __restrict__ Cp) {
    size_t t = (size_t)blockIdx.x * 256 + threadIdx.x;
    size_t base = t * 4;                      // over H*N
    int h = (int)(base >> 10);
    int n = (int)(base & 1023);
    float4 cr = *reinterpret_cast<const float4*>(Cr + base);
    float4 ci = *reinterpret_cast<const float4*>(Ci + base);
    u16* row = Cp + (size_t)h * K2;
    *reinterpret_cast<ushort4*>(row + n) =
        make_ushort4(f2bf(cr.x), f2bf(cr.y), f2bf(cr.z), f2bf(cr.w));
    *reinterpret_cast<ushort4*>(row + 1024 + n) =
        make_ushort4(f2bf(-ci.x), f2bf(-ci.y), f2bf(-ci.z), f2bf(-ci.w));
}

// ---------------------------------------------------------------------------
// GEMM1 (round-11 proven): 256x256 tile, BK=64, 8 waves (2Mx4N), dbuf slots.
// Interleaved schedule, 2 barriers/tile, race-free (r10 derivation):
//   READ kk0 | STAGE A1(t+1)->other slot | LGKM0 | MFMA kk0 qn01 |
//   READ kk1 | STAGE B1(t+1) | MFMA kk0 qn23 | LGKM0 | B1 |
//   STAGE A0(t+2)->slot s | MFMA kk1 qn01 | STAGE B0(t+2) | MFMA kk1 qn23 |
//   vmcnt(4) (tail: 0) | B2 (tile t+1 resident for all waves).
// 3-bit slot swizzle (slot ^ (row&7)), both-sides. Out = A*B^T, bf16 store.
// ---------------------------------------------------------------------------
__global__ __launch_bounds__(512, 2) void gemm_pipe(
    const u16* __restrict__ A, const u16* __restrict__ B, int Klen, int lda,
    u16* __restrict__ OutB, int ldo) {
    constexpr int ABYTES = 256 * 128;          // 32KB
    constexpr int SLOT   = 2 * ABYTES;         // 64KB
    __shared__ __attribute__((aligned(128))) char lds[2 * SLOT];
    const int tid = threadIdx.x;
    const int l   = tid & 63;
    const int w   = tid >> 6;
    const int wm  = w >> 2;            // 0..1
    const int wn  = w & 3;             // 0..3
    const long bm = (long)blockIdx.x * 256;
    const long bn = (long)blockIdx.y * 256;

    f32x4 acc[8][4];
#pragma unroll
    for (int i = 0; i < 8; ++i)
#pragma unroll
        for (int j = 0; j < 4; ++j) acc[i][j] = (f32x4){0.f, 0.f, 0.f, 0.f};

    const int    lr        = tid >> 3;
    const int    swzcol    = (((tid & 7) ^ (lr & 7)) << 4);
    const size_t rowstride = (size_t)lda * 2;
    const size_t a_src0    = (size_t)(bm + lr) * rowstride + swzcol;
    const size_t b_src0    = (size_t)(bn + lr) * rowstride + swzcol;
    const char*  Agb       = (const char*)A;
    const char*  Bgb       = (const char*)B;
    const int nt = Klen / 64;

    auto STAGE_A = [&](int kt, int h) {
        if (kt >= nt) return;
        const size_t kofs = (size_t)kt * 128;
        char* d = lds + (kt & 1) * SLOT + h * 16384 + tid * 16;
#pragma unroll
        for (int j = 0; j < 2; ++j)
            gload_lds16(Agb + a_src0 + (size_t)(h * 128 + j * 64) * rowstride + kofs,
                        d + j * 8192);
    };
    auto STAGE_B = [&](int kt, int h) {
        if (kt >= nt) return;
        const size_t kofs = (size_t)kt * 128;
        char* d = lds + (kt & 1) * SLOT + ABYTES + h * 16384 + tid * 16;
#pragma unroll
        for (int j = 0; j < 2; ++j)
            gload_lds16(Bgb + b_src0 + (size_t)(h * 128 + j * 64) * rowstride + kofs,
                        d + j * 8192);
    };

    const int l15   = l & 15;
    const int lslot = l >> 4;

    auto READ_A = [&](bf16x8 (&af)[8], const char* lA, int kk) {
#pragma unroll
        for (int mi = 0; mi < 8; ++mi) {
            int r   = wm * 128 + mi * 16 + l15;
            int sl3 = ((kk << 2) | lslot) ^ (r & 7);
            af[mi]  = *reinterpret_cast<const bf16x8*>(lA + r * 128 + sl3 * 16);
        }
    };
    auto READ_B = [&](bf16x8 (&bg)[4], const char* lB, int kk) {
#pragma unroll
        for (int ni = 0; ni < 4; ++ni) {
            int r   = wn * 64 + ni * 16 + l15;
            int sl3 = ((kk << 2) | lslot) ^ (r & 7);
            bg[ni]  = *reinterpret_cast<const bf16x8*>(lB + r * 128 + sl3 * 16);
        }
    };
    auto MFMA_Q = [&](bf16x8 (&af)[8], bf16x8 (&bg)[4], int qn) {
        __builtin_amdgcn_s_setprio(1);
#pragma unroll
        for (int mi = 0; mi < 8; ++mi)
#pragma unroll
            for (int nj = 0; nj < 2; ++nj)
                acc[mi][qn * 2 + nj] = __builtin_amdgcn_mfma_f32_16x16x32_bf16(
                    af[mi], bg[qn * 2 + nj], acc[mi][qn * 2 + nj], 0, 0, 0);
        __builtin_amdgcn_s_setprio(0);
    };

#define SBAR  do { __builtin_amdgcn_sched_barrier(0);                        \
    __builtin_amdgcn_s_barrier();                                            \
    __builtin_amdgcn_sched_barrier(0); } while (0)
#define LGKM0 do { asm volatile("s_waitcnt lgkmcnt(0)" ::: "memory");        \
    __builtin_amdgcn_sched_barrier(0); } while (0)

    STAGE_A(0, 0); STAGE_B(0, 0); STAGE_A(0, 1); STAGE_B(0, 1);
    STAGE_A(1, 0); STAGE_B(1, 0);
    asm volatile("s_waitcnt vmcnt(4)" ::: "memory");
    SBAR;

    bf16x8 af0[8], af1[8], bg0[4], bg1[4];

    for (int t = 0; t < nt; ++t) {
        const char* lA = lds + (t & 1) * SLOT;
        const char* lB = lA + ABYTES;
        READ_A(af0, lA, 0);
        READ_B(bg0, lB, 0);
        STAGE_A(t + 1, 1);                 // other slot; readers drained at
                                           // tile t-1's B1
        LGKM0;                             // af0/bg0 ready
        MFMA_Q(af0, bg0, 0);
        READ_A(af1, lA, 1);
        READ_B(bg1, lB, 1);
        STAGE_B(t + 1, 1);
        MFMA_Q(af0, bg0, 1);
        LGKM0;                             // af1/bg1 ready
        SBAR;                              // B1: all waves' slot-s reads done
        STAGE_A(t + 2, 0);
        MFMA_Q(af1, bg1, 0);
        STAGE_B(t + 2, 0);
        MFMA_Q(af1, bg1, 1);
        if (t < nt - 2) asm volatile("s_waitcnt vmcnt(4)" ::: "memory");
        else            asm volatile("s_waitcnt vmcnt(0)" ::: "memory");
        SBAR;                              // B2: tile t+1 resident, all waves
    }
#undef SBAR
#undef LGKM0

    // C/D layout: col = lane&15, row = (lane>>4)*4 + reg
#pragma unroll
    for (int mi = 0; mi < 8; ++mi) {
        const long row0 = bm + wm * 128 + mi * 16 + ((l >> 4) << 2);
#pragma unroll
        for (int ni = 0; ni < 4; ++ni) {
            const long col = bn + wn * 64 + ni * 16 + l15;
#pragma unroll
            for (int r = 0; r < 4; ++r)
                OutB[(size_t)(row0 + r) * ldo + col] = f2bf(acc[mi][ni][r]);
        }
    }
}

// ---------------------------------------------------------------------------
// GEMM2 (round-11 proven): 128x128 tile, 4 waves (2Mx2N), 64KB LDS ->
// 2 blocks/CU, same interleaved 2-barrier schedule (halves = 64 rows).
// Fused epilogue: OutF = acc + Dv[col] * Ur[row,col].
// ---------------------------------------------------------------------------
__global__ __launch_bounds__(256, 2) void gemm_small(
    const u16* __restrict__ A, const u16* __restrict__ B, int Klen, int lda,
    float* __restrict__ OutF, int ldo,
    const float* __restrict__ Dv, const float* __restrict__ Ur) {
    constexpr int ABYTES = 128 * 128;          // 16KB
    constexpr int SLOT   = 2 * ABYTES;         // 32KB (A+B)
    __shared__ __attribute__((aligned(128))) char lds[2 * SLOT];  // 64KB
    const int tid = threadIdx.x;
    const int l   = tid & 63;
    const int w   = tid >> 6;          // 0..3
    const int wm  = w >> 1;            // 0..1
    const int wn  = w & 1;             // 0..1
    const long bm = (long)blockIdx.x * 128;
    const long bn = (long)blockIdx.y * 128;

    f32x4 acc[4][4];
#pragma unroll
    for (int i = 0; i < 4; ++i)
#pragma unroll
        for (int j = 0; j < 4; ++j) acc[i][j] = (f32x4){0.f, 0.f, 0.f, 0.f};

    const int    lr        = tid >> 3;                    // 0..31
    const int    swzcol    = (((tid & 7) ^ (lr & 7)) << 4);
    const size_t rowstride = (size_t)lda * 2;
    const size_t a_src0    = (size_t)(bm + lr) * rowstride + swzcol;
    const size_t b_src0    = (size_t)(bn + lr) * rowstride + swzcol;
    const char*  Agb       = (const char*)A;
    const char*  Bgb       = (const char*)B;
    const int nt = Klen / 64;

    auto STAGE_A = [&](int kt, int h) {
        if (kt >= nt) return;
        const size_t kofs = (size_t)kt * 128;
        char* d = lds + (kt & 1) * SLOT + h * 8192 + tid * 16;
#pragma unroll
        for (int j = 0; j < 2; ++j)
            gload_lds16(Agb + a_src0 + (size_t)(h * 64 + j * 32) * rowstride + kofs,
                        d + j * 4096);
    };
    auto STAGE_B = [&](int kt, int h) {
        if (kt >= nt) return;
        const size_t kofs = (size_t)kt * 128;
        char* d = lds + (kt & 1) * SLOT + ABYTES + h * 8192 + tid * 16;
#pragma unroll
        for (int j = 0; j < 2; ++j)
            gload_lds16(Bgb + b_src0 + (size_t)(h * 64 + j * 32) * rowstride + kofs,
                        d + j * 4096);
    };

    const int l15   = l & 15;
    const int lslot = l >> 4;

    auto READ_A = [&](bf16x8 (&af)[4], const char* lA, int kk) {
#pragma unroll
        for (int mi = 0; mi < 4; ++mi) {
            int r   = wm * 64 + mi * 16 + l15;
            int sl3 = ((kk << 2) | lslot) ^ (r & 7);
            af[mi]  = *reinterpret_cast<const bf16x8*>(lA + r * 128 + sl3 * 16);
        }
    };
    auto READ_B = [&](bf16x8 (&bg)[4], const char* lB, int kk) {
#pragma unroll
        for (int ni = 0; ni < 4; ++ni) {
            int r   = wn * 64 + ni * 16 + l15;
            int sl3 = ((kk << 2) | lslot) ^ (r & 7);
            bg[ni]  = *reinterpret_cast<const bf16x8*>(lB + r * 128 + sl3 * 16);
        }
    };
    auto MFMA_Q = [&](bf16x8 (&af)[4], bf16x8 (&bg)[4], int qn) {
        __builtin_amdgcn_s_setprio(1);
#pragma unroll
        for (int mi = 0; mi < 4; ++mi)
#pragma unroll
            for (int nj = 0; nj < 2; ++nj)
                acc[mi][qn * 2 + nj] = __builtin_amdgcn_mfma_f32_16x16x32_bf16(
                    af[mi], bg[qn * 2 + nj], acc[mi][qn * 2 + nj], 0, 0, 0);
        __builtin_amdgcn_s_setprio(0);
    };

#define SBAR  do { __builtin_amdgcn_sched_barrier(0);                        \
    __builtin_amdgcn_s_barrier();                                            \
    __builtin_amdgcn_sched_barrier(0); } while (0)
#define LGKM0 do { asm volatile("s_waitcnt lgkmcnt(0)" ::: "memory");        \
    __builtin_amdgcn_sched_barrier(0); } while (0)

    STAGE_A(0, 0); STAGE_B(0, 0); STAGE_A(0, 1); STAGE_B(0, 1);
    STAGE_A(1, 0); STAGE_B(1, 0);
    asm volatile("s_waitcnt vmcnt(4)" ::: "memory");
    SBAR;

    bf16x8 af0[4], af1[4], bg0[4], bg1[4];

    for (int t = 0; t < nt; ++t) {
        const char* lA = lds + (t & 1) * SLOT;
        const char* lB = lA + ABYTES;
        READ_A(af0, lA, 0);
        READ_B(bg0, lB, 0);
        STAGE_A(t + 1, 1);
        LGKM0;
        MFMA_Q(af0, bg0, 0);
        READ_A(af1, lA, 1);
        READ_B(bg1, lB, 1);
        STAGE_B(t + 1, 1);
        MFMA_Q(af0, bg0, 1);
        LGKM0;
        SBAR;                              // B1
        STAGE_A(t + 2, 0);
        MFMA_Q(af1, bg1, 0);
        STAGE_B(t + 2, 0);
        MFMA_Q(af1, bg1, 1);
        if (t < nt - 2) asm volatile("s_waitcnt vmcnt(4)" ::: "memory");
        else            asm volatile("s_waitcnt vmcnt(0)" ::: "memory");
        SBAR;                              // B2
    }
#undef SBAR
#undef LGKM0

    // epilogue with fused D*u_r
#pragma unroll
    for (int mi = 0; mi < 4; ++mi) {
        const long row0 = bm + wm * 64 + mi * 16 + ((l >> 4) << 2);
#pragma unroll
        for (int ni = 0; ni < 4; ++ni) {
            const long col = bn + wn * 64 + ni * 16 + l15;
            const float d = Dv[col];
#pragma unroll
            for (int r = 0; r < 4; ++r) {
                size_t o = (size_t)(row0 + r) * ldo + col;
                OutF[o] = acc[mi][ni][r] + d * Ur[o];
            }
        }
    }
}

// ---------------------------------------------------------------------------
// Scan pass A (read-only): per-(chunk, channel-pair) final states only.
// ---------------------------------------------------------------------------
__global__ void scan_sum(const u16* __restrict__ X,
                         const float* __restrict__ nu_log,
                         const float* __restrict__ theta_log,
                         float* __restrict__ bcr, float* __restrict__ bci) {
    int n0 = (blockIdx.y * 256 + threadIdx.x) * 2;   // channel pair
    int c  = blockIdx.x;
    float lr0, li0, lr1, li1;
    {
        float m0 = expf(-expf(nu_log[n0]));
        float t0 = expf(theta_log[n0]);
        float s0, c0; sincosf(t0, &s0, &c0);
        lr0 = m0 * c0; li0 = m0 * s0;
        float m1 = expf(-expf(nu_log[n0 + 1]));
        float t1 = expf(theta_log[n0 + 1]);
        float s1, c1; sincosf(t1, &s1, &c1);
        lr1 = m1 * c1; li1 = m1 * s1;
    }
    float sr0 = 0.f, si0 = 0.f, sr1 = 0.f, si1 = 0.f;
    size_t base = (size_t)c * CHUNK * K2 + n0;
    for (int j = 0; j < CHUNK; ++j) {
        size_t idx = base + (size_t)j * K2;
        unsigned int ru = *reinterpret_cast<const unsigned int*>(X + idx);
        unsigned int iu = *reinterpret_cast<const unsigned int*>(X + idx + 1024);
        float br0 = bf2f((u16)ru), br1 = bf2f((u16)(ru >> 16));
        float bi0 = bf2f((u16)iu), bi1 = bf2f((u16)(iu >> 16));
        float nr0 = lr0 * sr0 - li0 * si0 + br0;
        float ni0 = lr0 * si0 + li0 * sr0 + bi0;
        sr0 = nr0; si0 = ni0;
        float nr1 = lr1 * sr1 - li1 * si1 + br1;
        float ni1 = lr1 * si1 + li1 * sr1 + bi1;
        sr1 = nr1; si1 = ni1;
    }
    bcr[(size_t)n0 * NCHUNK + c] = sr0; bci[(size_t)n0 * NCHUNK + c] = si0;
    bcr[(size_t)(n0 + 1) * NCHUNK + c] = sr1; bci[(size_t)(n0 + 1) * NCHUNK + c] = si1;
}

// ---------------------------------------------------------------------------
// Scan pass B: wave-parallel scan over NCHUNK=256 chunk summaries.
// One wave per channel; lane owns 4 chunks; 6-step shfl_up scan.
// ---------------------------------------------------------------------------
__global__ void scan_carry(const float* __restrict__ bcr, const float* __restrict__ bci,
                           const float* __restrict__ nu_log,
                           const float* __restrict__ theta_log,
                           float* __restrict__ car, float* __restrict__ cai) {
    const int lane = threadIdx.x & 63;
    const int n    = blockIdx.x * 4 + (threadIdx.x >> 6);
    float mag = expf(-(float)CHUNK * expf(nu_log[n]));
    float ang = (float)CHUNK * expf(theta_log[n]);
    float sL, cL; sincosf(ang, &sL, &cL);
    const float Lr = mag * cL, Li = mag * sL;
    const size_t base = (size_t)n * NCHUNK + lane * 4;
    float4 br4 = *reinterpret_cast<const float4*>(bcr + base);
    float4 bi4 = *reinterpret_cast<const float4*>(bci + base);
    float br = br4.x, bi = bi4.x;
    { float tr = Lr * br - Li * bi + br4.y, ti = Lr * bi + Li * br + bi4.y; br = tr; bi = ti; }
    { float tr = Lr * br - Li * bi + br4.z, ti = Lr * bi + Li * br + bi4.z; br = tr; bi = ti; }
    { float tr = Lr * br - Li * bi + br4.w, ti = Lr * bi + Li * br + bi4.w; br = tr; bi = ti; }
    float L2r = Lr * Lr - Li * Li, L2i = 2.f * Lr * Li;
    float Ar = L2r * L2r - L2i * L2i, Ai = 2.f * L2r * L2i;   // L^4
#pragma unroll
    for (int d = 1; d < 64; d <<= 1) {
        float pAr = __shfl_up(Ar, d);
        float pAi = __shfl_up(Ai, d);
        float pbr = __shfl_up(br, d);
        float pbi = __shfl_up(bi, d);
        if (lane >= d) {
            float nbr = Ar * pbr - Ai * pbi + br;
            float nbi = Ar * pbi + Ai * pbr + bi;
            float nAr = Ar * pAr - Ai * pAi;
            float nAi = Ar * pAi + Ai * pAr;
            br = nbr; bi = nbi; Ar = nAr; Ai = nAi;
        }
    }
    float sr = __shfl_up(br, 1);
    float si = __shfl_up(bi, 1);
    if (lane == 0) { sr = 0.f; si = 0.f; }
    float4 or4, oi4;
    or4.x = sr; oi4.x = si;
    { float tr = Lr * sr - Li * si + br4.x, ti = Lr * si + Li * sr + bi4.x; sr = tr; si = ti; }
    or4.y = sr; oi4.y = si;
    { float tr = Lr * sr - Li * si + br4.y, ti = Lr * si + Li * sr + bi4.y; sr = tr; si = ti; }
    or4.z = sr; oi4.z = si;
    { float tr = Lr * sr - Li * si + br4.z, ti = Lr * si + Li * sr + bi4.z; sr = tr; si = ti; }
    or4.w = sr; oi4.w = si;
    *reinterpret_cast<float4*>(car + base) = or4;
    *reinterpret_cast<float4*>(cai + base) = oi4;
}

// ---------------------------------------------------------------------------
// Scan pass C: re-scan each chunk seeded with carry-in; write final x (bf16).
// ---------------------------------------------------------------------------
__global__ void scan_apply(u16* __restrict__ X,
                           const float* __restrict__ nu_log,
                           const float* __restrict__ theta_log,
                           const float* __restrict__ car, const float* __restrict__ cai) {
    int n0 = (blockIdx.y * 256 + threadIdx.x) * 2;
    int c  = blockIdx.x;
    float lr0, li0, lr1, li1;
    {
        float m0 = expf(-expf(nu_log[n0]));
        float t0 = expf(theta_log[n0]);
        float s0, c0; sincosf(t0, &s0, &c0);
        lr0 = m0 * c0; li0 = m0 * s0;
        float m1 = expf(-expf(nu_log[n0 + 1]));
        float t1 = expf(theta_log[n0 + 1]);
        float s1, c1; sincosf(t1, &s1, &c1);
        lr1 = m1 * c1; li1 = m1 * s1;
    }
    float sr0 = car[(size_t)n0 * NCHUNK + c],       si0 = cai[(size_t)n0 * NCHUNK + c];
    float sr1 = car[(size_t)(n0 + 1) * NCHUNK + c], si1 = cai[(size_t)(n0 + 1) * NCHUNK + c];
    size_t base = (size_t)c * CHUNK * K2 + n0;
    for (int j = 0; j < CHUNK; ++j) {
        size_t idx = base + (size_t)j * K2;
        unsigned int ru = *reinterpret_cast<const unsigned int*>(X + idx);
        unsigned int iu = *reinterpret_cast<const unsigned int*>(X + idx + 1024);
        float br0 = bf2f((u16)ru), br1 = bf2f((u16)(ru >> 16));
        float bi0 = bf2f((u16)iu), bi1 = bf2f((u16)(iu >> 16));
        float nr0 = lr0 * sr0 - li0 * si0 + br0;
        float ni0 = lr0 * si0 + li0 * sr0 + bi0;
        sr0 = nr0; si0 = ni0;
        float nr1 = lr1 * sr1 - li1 * si1 + br1;
        float ni1 = lr1 * si1 + li1 * sr1 + bi1;
        sr1 = nr1; si1 = ni1;
        *reinterpret_cast<unsigned int*>(X + idx) =
            (unsigned int)f2bf(sr0) | ((unsigned int)f2bf(sr1) << 16);
        *reinterpret_cast<unsigned int*>(X + idx + 1024) =
            (unsigned int)f2bf(si0) | ((unsigned int)f2bf(si1) << 16);
    }
}

// ---------------------------------------------------------------------------
// Launch
// ---------------------------------------------------------------------------
extern "C" void kernel_launch(void* const* d_in, const int* in_sizes, int n_in,
                              void* d_out, int out_size, void* d_ws, size_t ws_size,
                              hipStream_t stream) {
    (void)in_sizes; (void)n_in; (void)out_size; (void)ws_size;
    const float* input_real = (const float*)d_in[0];
    const float* input_imag = (const float*)d_in[1];
    const float* nu_log     = (const float*)d_in[2];
    const float* theta_log  = (const float*)d_in[3];
    const float* B_real     = (const float*)d_in[4];
    const float* B_imag     = (const float*)d_in[5];
    const float* C_real     = (const float*)d_in[6];
    const float* C_imag     = (const float*)d_in[7];
    const float* D          = (const float*)d_in[8];
    const float* gamma_log  = (const float*)d_in[9];
    float* y = (float*)d_out;

    // Workspace layout (bytes):
    // [2M, 34M)  A' bf16 [8192][2048]  (dead after gemm1)
    //   [2M, 6M)   Cp aliases A' head  (alive after pack_C)
    // [34M, 42M) Bp bf16 [2048][2048]  (dead after gemm1)
    //   [34M, 38M) bcr/bci/car/cai (4 x 1MB) alias Bp (alive after gemm1)
    // [42M, 74M) X  bf16 [8192][2048]  (Bu -> x in place)
    char* ws = (char*)d_ws;
    u16* Ap   = (u16*)(ws + ((size_t)2 << 20));
    u16* Cp   = Ap;                                 // alias: used after gemm1
    u16* Bp   = (u16*)(ws + ((size_t)34 << 20));
    float* bcr = (float*)(ws + ((size_t)34 << 20)); // alias Bp: used after gemm1
    float* bci = bcr + NCHUNK * N_DIM;
    float* car = bci + NCHUNK * N_DIM;
    float* cai = car + NCHUNK * N_DIM;
    u16* X    = (u16*)(ws + ((size_t)42 << 20));

    pack_ub<<<(L_SEQ * H_DIM / 4) / 256 + (N_DIM * H_DIM / 4) / 256, 256, 0, stream>>>(
        input_real, input_imag, B_real, B_imag, gamma_log, Ap, Bp);
    // GEMM1: 256x256 tile, grid 32x8 = 256 blocks (1/CU), K=2048
    gemm_pipe<<<dim3(L_SEQ / 256, K2 / 256), 512, 0, stream>>>(
        Ap, Bp, K2, K2, X, K2);
    scan_sum<<<dim3(NCHUNK, N_DIM / 512), 256, 0, stream>>>(
        X, nu_log, theta_log, bcr, bci);
    scan_carry<<<N_DIM / 4, 256, 0, stream>>>(bcr, bci, nu_log, theta_log, car, cai);
    scan_apply<<<dim3(NCHUNK, N_DIM / 512), 256, 0, stream>>>(
        X, nu_log, theta_log, car, cai);
    pack_C<<<(H_DIM * N_DIM / 4) / 256, 256, 0, stream>>>(C_real, C_imag, Cp);
    // GEMM2: 128x128 tile, grid 64x8 = 512 blocks (2/CU), K=2048, fused D*u
    gemm_small<<<dim3(L_SEQ / 128, H_DIM / 128), 256, 0, stream>>>(
        X, Cp, K2, K2, y, H_DIM, D, input_real);
}